// Round 10
// baseline (164.967 us; speedup 1.0000x reference)
//
#include <hip/hip_runtime.h>
#include <hip/hip_bf16.h>

// Problem geometry (fixed)
#define BDIM 4
#define CDIM 256
#define HDIM 64
#define WDIM 64
#define LDIM 4096   // H*W
#define ROWS 16384  // B*L

typedef __attribute__((ext_vector_type(8))) short short8;
typedef __attribute__((ext_vector_type(4))) float f32x4;
typedef __attribute__((ext_vector_type(16))) float f32x16;
typedef unsigned int u32;

static __device__ __forceinline__ unsigned short f2bf(float f) {
    unsigned int x = __float_as_uint(f);
    unsigned int r = (x + 0x7fffu + ((x >> 16) & 1u)) >> 16;   // RNE
    return (unsigned short)r;
}
static __device__ __forceinline__ float bf2f(unsigned int u) {
    return __uint_as_float(u << 16);
}
static __device__ __forceinline__ u32 pk2(float a, float b) {
    return (u32)f2bf(a) | ((u32)f2bf(b) << 16);
}
static __device__ __forceinline__ u32 cvtpk(float lo, float hi) {
    u32 r;
    asm("v_cvt_pk_bf16_f32 %0, %1, %2" : "=v"(r) : "v"(lo), "v"(hi));
    return r;
}

// ---------------------------------------------------------------------------
// fp32 -> bf16 conversion of all four weight matrices in ONE launch.
// ---------------------------------------------------------------------------
__global__ __launch_bounds__(256) void cvt4_kernel(
    const float* __restrict__ a, const float* __restrict__ b,
    const float* __restrict__ c, const float* __restrict__ d,
    unsigned short* __restrict__ oa, unsigned short* __restrict__ ob,
    unsigned short* __restrict__ oc, unsigned short* __restrict__ od)
{
    int i = blockIdx.x * 256 + threadIdx.x;
    const float* in; unsigned short* out; int off;
    if (i < 32768)       { in = a; out = oa; off = i; }
    else if (i < 49152)  { in = b; out = ob; off = i - 32768; }
    else if (i < 114688) { in = c; out = oc; off = i - 49152; }
    else if (i < 180224) { in = d; out = od; off = i - 114688; }
    else return;
    float4 f = reinterpret_cast<const float4*>(in)[off];
    reinterpret_cast<uint2*>(out)[off] = make_uint2(pk2(f.x, f.y), pk2(f.z, f.w));
}

// ---------------------------------------------------------------------------
// LayerNorm over C=256 -> bf16 out (+ optional raw fp32 transpose copy xT).
// ---------------------------------------------------------------------------
__global__ __launch_bounds__(256) void norm_kernel(
    const float* __restrict__ xin,
    const float* __restrict__ w, const float* __restrict__ b,
    unsigned short* __restrict__ out,
    float* __restrict__ xT,
    int transposed_in)
{
    int wave = threadIdx.x >> 6;
    int lane = threadIdx.x & 63;
    int row = blockIdx.x * 4 + wave;
    float v[4];
    float sum = 0.f, sumsq = 0.f;
    if (transposed_in) {
        int bb = row >> 12;
        int l = row & 4095;
        const float* xb = xin + (size_t)bb * (CDIM * LDIM) + l;
        #pragma unroll
        for (int i = 0; i < 4; ++i) {
            int c = lane + i * 64;
            float t = xb[(size_t)c * LDIM];
            v[i] = t; sum += t; sumsq += t * t;
        }
    } else {
        const float* xr = xin + (size_t)row * CDIM;
        #pragma unroll
        for (int i = 0; i < 4; ++i) {
            float t = xr[lane + i * 64];
            v[i] = t; sum += t; sumsq += t * t;
        }
    }
    #pragma unroll
    for (int off = 32; off > 0; off >>= 1) {
        sum   += __shfl_xor(sum, off);
        sumsq += __shfl_xor(sumsq, off);
    }
    float mean = sum * (1.f / 256.f);
    float var  = sumsq * (1.f / 256.f) - mean * mean;
    float inv  = rsqrtf(var + 1e-5f);
    unsigned short* orow = out + (size_t)row * CDIM;
    #pragma unroll
    for (int i = 0; i < 4; ++i) {
        int c = lane + i * 64;
        if (xT) xT[(size_t)row * CDIM + c] = v[i];
        orow[c] = f2bf((v[i] - mean) * inv * w[c] + b[c]);
    }
}

// ---------------------------------------------------------------------------
// bf16 MFMA GEMM: C = A @ B^T (+ bias / gelu / resid), fp32 accumulate.
// 64x64 tile, BK=32, 4 waves (2x2), 2x2 frags/wave, dbuf global_load_lds,
// both-sides XOR slot swizzle, bijective XCD chunk swizzle.
// mode: 0 plain->f32; 1 plain->bf16; 2 +bias,gelu->bf16; 3 +bias+resid->f32
// ---------------------------------------------------------------------------
__global__ __launch_bounds__(256) void mfma_gemm(
    const unsigned short* __restrict__ A,
    const unsigned short* __restrict__ Bm,
    const float* __restrict__ bias,
    const float* __restrict__ resid,
    void* __restrict__ outp,
    int N, int K, int mode)
{
    __shared__ unsigned short As[2][64 * 32];
    __shared__ unsigned short Bs[2][64 * 32];
    int tid  = threadIdx.x;
    int lane = tid & 63;
    int w    = tid >> 6;
    int wr   = w >> 1, wc = w & 1;
    int l15  = lane & 15, kbl = lane >> 4;

    int gx  = gridDim.x;
    int nwg = gx * gridDim.y;
    int bid = blockIdx.y * gx + blockIdx.x;
    int cpx = nwg >> 3;
    int swz = (bid & 7) * cpx + (bid >> 3);
    int n0 = (swz % gx) * 64;
    int m0 = (swz / gx) * 64;

    f32x4 acc[2][2];
    #pragma unroll
    for (int m = 0; m < 2; ++m)
        #pragma unroll
        for (int n = 0; n < 2; ++n)
            acc[m][n] = (f32x4){0.f, 0.f, 0.f, 0.f};

    int srow = tid >> 2;
    int sp   = tid & 3;
    int ss   = sp ^ (srow & 3);
    auto STAGE = [&](int buf, int k0) {
        const unsigned short* ga = A  + (size_t)(m0 + srow) * K + k0 + ss * 8;
        const unsigned short* gb = Bm + (size_t)(n0 + srow) * K + k0 + ss * 8;
        __builtin_amdgcn_global_load_lds(
            (const __attribute__((address_space(1))) void*)ga,
            (__attribute__((address_space(3))) void*)(As[buf] + tid * 8), 16, 0, 0);
        __builtin_amdgcn_global_load_lds(
            (const __attribute__((address_space(1))) void*)gb,
            (__attribute__((address_space(3))) void*)(Bs[buf] + tid * 8), 16, 0, 0);
    };

    STAGE(0, 0);
    __syncthreads();

    int cur = 0;
    for (int k0 = 0; k0 < K; k0 += 32) {
        if (k0 + 32 < K) STAGE(cur ^ 1, k0 + 32);

        short8 af[2], bf[2];
        #pragma unroll
        for (int m = 0; m < 2; ++m) {
            int row = wr * 32 + m * 16 + l15;
            af[m] = *reinterpret_cast<const short8*>(
                As[cur] + row * 32 + (kbl ^ (row & 3)) * 8);
        }
        #pragma unroll
        for (int n = 0; n < 2; ++n) {
            int row = wc * 32 + n * 16 + l15;
            bf[n] = *reinterpret_cast<const short8*>(
                Bs[cur] + row * 32 + (kbl ^ (row & 3)) * 8);
        }
        #pragma unroll
        for (int m = 0; m < 2; ++m)
            #pragma unroll
            for (int n = 0; n < 2; ++n)
                acc[m][n] = __builtin_amdgcn_mfma_f32_16x16x32_bf16(
                    af[m], bf[n], acc[m][n], 0, 0, 0);

        __syncthreads();
        cur ^= 1;
    }

    int r0 = kbl * 4;
    #pragma unroll
    for (int m = 0; m < 2; ++m) {
        #pragma unroll
        for (int n = 0; n < 2; ++n) {
            int col = n0 + wc * 32 + n * 16 + l15;
            #pragma unroll
            for (int r = 0; r < 4; ++r) {
                int row = m0 + wr * 32 + m * 16 + r0 + r;
                float v = acc[m][n][r];
                if (mode == 0) {
                    ((float*)outp)[(size_t)row * N + col] = v;
                } else if (mode == 1) {
                    ((unsigned short*)outp)[(size_t)row * N + col] = f2bf(v);
                } else if (mode == 2) {
                    v += bias[col];
                    v = 0.5f * v * (1.f + erff(v * 0.70710678118654752f));
                    ((unsigned short*)outp)[(size_t)row * N + col] = f2bf(v);
                } else {
                    v += bias[col] + resid[(size_t)row * N + col];
                    ((float*)outp)[(size_t)row * N + col] = v;
                }
            }
        }
    }
}

// ---------------------------------------------------------------------------
// MFMA windowed attention + fused LePE, query-split for occupancy.
// grid = 512: bid>>1 = (window,head), bid&1 = query half (256 q each).
// Each block stages the FULL K/V window in LDS (67 KB -> 2 blocks/CU,
// 4 waves/SIMD); each of 8 waves handles ONE 32-query slice.
// Swapped QK^T; exp2-domain online softmax; hoisted Q-frags; tree/defer max;
// cvt_pk packing; permlane32_swap; setprio around MFMA clusters.
// ---------------------------------------------------------------------------
__global__ __launch_bounds__(512) void attn_kernel(
    const unsigned short* __restrict__ qkv,   // ROWS x 512 bf16
    const float* __restrict__ gw0, const float* __restrict__ gb0,
    const float* __restrict__ gw1, const float* __restrict__ gb1,
    unsigned short* __restrict__ att)         // ROWS x 256 bf16
{
    __shared__ unsigned short Kbuf[512 * 32]; // [row][d], slot ^= (row>>1)&3
    __shared__ unsigned short Vt[32 * 512];   // [d][key], slot ^= d&7
    __shared__ float gwl[288];
    __shared__ float gbl[32];
    const int bid = blockIdx.x;
    const int qh  = bid & 1;                  // query half
    const int wh  = bid >> 1;
    const int br = wh >> 7, head = wh & 3, win = (wh >> 2) & 31;
    const int bb = win >> 3, wi = win & 7;
    const int tid = threadIdx.x;
    const int qk_off = br * 128 + head * 32;
    const int v_off = 256 + qk_off;
    // sqrt(32^-0.5 * log2(e)) : folds the softmax scale AND exp->exp2 factor
    const float sscale = 0.50500977f;

    {
        const float* gw = br ? gw1 : gw0;
        const float* gb = br ? gb1 : gb0;
        if (tid < 288) gwl[tid] = gw[(head * 32) * 9 + tid];
        else if (tid >= 480) gbl[tid - 480] = gb[head * 32 + tid - 480];
    }
    // ---- stage K (scaled) ----
    {
        int t = tid;
        int l = (br == 0) ? ((t >> 3) * 64 + wi * 8 + (t & 7)) : (wi * 512 + t);
        const unsigned short* src = qkv + ((size_t)(bb * 4096 + l)) * 512 + qk_off;
        #pragma unroll
        for (int s = 0; s < 4; ++s) {
            uint4 raw = *reinterpret_cast<const uint4*>(src + s * 8);
            u32 rw[4] = {raw.x, raw.y, raw.z, raw.w};
            u32 ow[4];
            #pragma unroll
            for (int i = 0; i < 4; ++i) {
                float lo = bf2f(rw[i] & 0xffffu) * sscale;
                float hi = bf2f(rw[i] >> 16) * sscale;
                ow[i] = cvtpk(lo, hi);
            }
            int sl = s ^ ((t >> 1) & 3);
            *reinterpret_cast<uint4*>(Kbuf + t * 32 + sl * 8) =
                make_uint4(ow[0], ow[1], ow[2], ow[3]);
        }
    }
    // ---- stage V transposed ----
    {
        int kp = (tid & 255) * 2, dh = tid >> 8;
        int kq = kp + 1;
        int l0 = (br == 0) ? ((kp >> 3) * 64 + wi * 8 + (kp & 7)) : (wi * 512 + kp);
        int l1 = (br == 0) ? ((kq >> 3) * 64 + wi * 8 + (kq & 7)) : (wi * 512 + kq);
        const unsigned short* v0 = qkv + ((size_t)(bb * 4096 + l0)) * 512 + v_off + dh * 16;
        const unsigned short* v1 = qkv + ((size_t)(bb * 4096 + l1)) * 512 + v_off + dh * 16;
        uint4 a0 = *reinterpret_cast<const uint4*>(v0);
        uint4 a1 = *reinterpret_cast<const uint4*>(v0 + 8);
        uint4 b0 = *reinterpret_cast<const uint4*>(v1);
        uint4 b1 = *reinterpret_cast<const uint4*>(v1 + 8);
        u32 av[8] = {a0.x, a0.y, a0.z, a0.w, a1.x, a1.y, a1.z, a1.w};
        u32 bv[8] = {b0.x, b0.y, b0.z, b0.w, b1.x, b1.y, b1.z, b1.w};
        int slot = kp >> 3;
        #pragma unroll
        for (int dd = 0; dd < 16; ++dd) {
            u32 x0 = (dd & 1) ? (av[dd >> 1] >> 16) : (av[dd >> 1] & 0xffffu);
            u32 x1 = (dd & 1) ? (bv[dd >> 1] >> 16) : (bv[dd >> 1] & 0xffffu);
            int d = dh * 16 + dd;
            int sl = slot ^ (d & 7);
            *reinterpret_cast<u32*>(Vt + d * 512 + sl * 8 + (kp & 7)) = x0 | (x1 << 16);
        }
    }
    __syncthreads();

    const int lane = tid & 63;
    const int w = tid >> 6;
    const int ql = lane & 31;
    const int h = lane >> 5;
    const int qrow = qh * 256 + w * 32 + ql;   // this wave's 32-query slice

    // hoisted Q-fragments (kt-invariant)
    short8 qf0, qf1;
    {
        int sw = (qrow >> 1) & 3;
        qf0 = *reinterpret_cast<const short8*>(Kbuf + qrow * 32 + ((0 + h) ^ sw) * 8);
        qf1 = *reinterpret_cast<const short8*>(Kbuf + qrow * 32 + ((2 + h) ^ sw) * 8);
    }

    f32x16 O;
    #pragma unroll
    for (int i = 0; i < 16; ++i) O[i] = 0.f;
    float M = -1e30f, SU = 0.f;

    for (int kt = 0; kt < 16; ++kt) {
        int k0 = kt * 32;
        int krow = k0 + ql;
        int ksw = (krow >> 1) & 3;
        short8 kf0 = *reinterpret_cast<const short8*>(Kbuf + krow * 32 + ((0 + h) ^ ksw) * 8);
        short8 kf1 = *reinterpret_cast<const short8*>(Kbuf + krow * 32 + ((2 + h) ^ ksw) * 8);
        int ko0 = k0 + h * 8;
        int ko1 = k0 + 16 + h * 8;
        short8 vf0 = *reinterpret_cast<const short8*>(Vt + ql * 512 + ((ko0 >> 3) ^ (ql & 7)) * 8);
        short8 vf1 = *reinterpret_cast<const short8*>(Vt + ql * 512 + ((ko1 >> 3) ^ (ql & 7)) * 8);

        f32x16 sacc;
        #pragma unroll
        for (int i = 0; i < 16; ++i) sacc[i] = 0.f;
        __builtin_amdgcn_s_setprio(1);
        sacc = __builtin_amdgcn_mfma_f32_32x32x16_bf16(kf0, qf0, sacc, 0, 0, 0);
        sacc = __builtin_amdgcn_mfma_f32_32x32x16_bf16(kf1, qf1, sacc, 0, 0, 0);
        __builtin_amdgcn_s_setprio(0);
        // tree max (max3-fusable, short dep chain)
        float t8[8];
        #pragma unroll
        for (int r = 0; r < 8; ++r) t8[r] = fmaxf(sacc[r], sacc[r + 8]);
        float t4[4];
        #pragma unroll
        for (int r = 0; r < 4; ++r) t4[r] = fmaxf(t8[r], t8[r + 4]);
        float mx = fmaxf(fmaxf(t4[0], t4[1]), fmaxf(t4[2], t4[3]));
        mx = fmaxf(mx, __shfl_xor(mx, 32));
        bool defer = __all(mx <= M + 8.f);   // defer-max, THR=8 (log2 units)
        float nm = defer ? M : fmaxf(M, mx);
        float p[16];
        float ps = 0.f;
        #pragma unroll
        for (int r = 0; r < 16; ++r) { p[r] = exp2f(sacc[r] - nm); ps += p[r]; }
        ps += __shfl_xor(ps, 32);
        if (defer) {
            SU += ps;
        } else {
            float fs = exp2f(M - nm);
            SU = SU * fs + ps;
            #pragma unroll
            for (int r = 0; r < 16; ++r) O[r] *= fs;
            M = nm;
        }
        u32 P0 = cvtpk(p[0],  p[1]),  P1 = cvtpk(p[2],  p[3]);
        u32 P2 = cvtpk(p[4],  p[5]),  P3 = cvtpk(p[6],  p[7]);
        u32 P4 = cvtpk(p[8],  p[9]),  P5 = cvtpk(p[10], p[11]);
        u32 P6 = cvtpk(p[12], p[13]), P7 = cvtpk(p[14], p[15]);
        asm volatile("v_permlane32_swap_b32 %0, %1" : "+v"(P0), "+v"(P2));
        asm volatile("v_permlane32_swap_b32 %0, %1" : "+v"(P1), "+v"(P3));
        asm volatile("v_permlane32_swap_b32 %0, %1" : "+v"(P4), "+v"(P6));
        asm volatile("v_permlane32_swap_b32 %0, %1" : "+v"(P5), "+v"(P7));
        union { u32 u[4]; short8 s; } c0, c1;
        c0.u[0] = P0; c0.u[1] = P1; c0.u[2] = P2; c0.u[3] = P3;
        c1.u[0] = P4; c1.u[1] = P5; c1.u[2] = P6; c1.u[3] = P7;
        __builtin_amdgcn_s_setprio(1);
        O = __builtin_amdgcn_mfma_f32_32x32x16_bf16(vf0, c0.s, O, 0, 0, 0);
        O = __builtin_amdgcn_mfma_f32_32x32x16_bf16(vf1, c1.s, O, 0, 0, 0);
        __builtin_amdgcn_s_setprio(0);
    }

    // epilogue: normalize + fused LePE from LDS, write bf16.
    {
        float inv = 1.f / SU;
        int hs  = (br == 0) ? (qrow >> 3) : (qrow >> 6);
        int wsx = (br == 0) ? (qrow & 7)  : (qrow & 63);

        float lep[16];
        #pragma unroll
        for (int r = 0; r < 16; ++r) {
            int d = (r & 3) + 8 * (r >> 2) + 4 * h;
            lep[r] = gbl[d];
        }
        #pragma unroll
        for (int dy = -1; dy <= 1; ++dy) {
            int hn = hs + dy;
            bool okh = (br == 0) ? ((unsigned)hn < 64u) : ((unsigned)hn < 8u);
            #pragma unroll
            for (int dx = -1; dx <= 1; ++dx) {
                int wn = wsx + dx;
                bool okw = (br == 0) ? ((unsigned)wn < 8u) : ((unsigned)wn < 64u);
                if (okh && okw) {
                    int key = (br == 0) ? (hn * 8 + wn) : (hn * 64 + wn);
                    int t = (dy + 1) * 3 + (dx + 1);
                    #pragma unroll
                    for (int r = 0; r < 16; ++r) {
                        int d = (r & 3) + 8 * (r >> 2) + 4 * h;
                        float vv = bf2f((u32)(unsigned short)
                            Vt[d * 512 + (((key >> 3) ^ (d & 7)) * 8 + (key & 7))]);
                        lep[r] += vv * gwl[d * 9 + t];
                    }
                }
            }
        }

        int l = (br == 0) ? ((qrow >> 3) * 64 + wi * 8 + (qrow & 7)) : (wi * 512 + qrow);
        unsigned short* orow = att + ((size_t)(bb * 4096 + l)) * 256 + qk_off;
        #pragma unroll
        for (int g = 0; g < 4; ++g) {
            u32 lo = pk2(O[4 * g] * inv + lep[4 * g],
                         O[4 * g + 1] * inv + lep[4 * g + 1]);
            u32 hi = pk2(O[4 * g + 2] * inv + lep[4 * g + 2],
                         O[4 * g + 3] * inv + lep[4 * g + 3]);
            *reinterpret_cast<uint2*>(orow + 8 * g + 4 * h) = make_uint2(lo, hi);
        }
    }
}

// ---------------------------------------------------------------------------
extern "C" void kernel_launch(void* const* d_in, const int* in_sizes, int n_in,
                              void* d_out, int out_size, void* d_ws, size_t ws_size,
                              hipStream_t stream) {
    const float* x     = (const float*)d_in[0];
    const float* n1w   = (const float*)d_in[1];
    const float* n1b   = (const float*)d_in[2];
    const float* qkvw  = (const float*)d_in[3];
    const float* gw0   = (const float*)d_in[4];
    const float* gb0   = (const float*)d_in[5];
    const float* gw1   = (const float*)d_in[6];
    const float* gb1   = (const float*)d_in[7];
    const float* projw = (const float*)d_in[8];
    const float* projb = (const float*)d_in[9];
    const float* n2w   = (const float*)d_in[10];
    const float* n2b   = (const float*)d_in[11];
    const float* fc1w  = (const float*)d_in[12];
    const float* fc1b  = (const float*)d_in[13];
    const float* fc2w  = (const float*)d_in[14];
    const float* fc2b  = (const float*)d_in[15];
    float* out = (float*)d_out;
    char* wsb  = (char*)d_ws;

    // workspace layout (bytes)
    float*          xT   = (float*)wsb;                          // 16,777,216
    unsigned short* qkv  = (unsigned short*)(wsb + 16777216);    // 16,777,216
    unsigned short* att  = (unsigned short*)(wsb + 33554432);    //  8,388,608
    unsigned short* img  = (unsigned short*)(wsb + 41943040);    //  8,388,608
    unsigned short* wq   = (unsigned short*)(wsb + 50331648);    //    262,144
    unsigned short* wp   = (unsigned short*)(wsb + 50593792);    //    131,072
    unsigned short* w1   = (unsigned short*)(wsb + 50724864);    //    524,288
    unsigned short* w2   = (unsigned short*)(wsb + 51249152);    //    524,288
    unsigned short* ynorm  = img;                                // reuse
    unsigned short* hidden = (unsigned short*)wsb;               // overlays xT+qkv (dead by fc1)

    // weight fp32 -> bf16 (one launch)
    cvt4_kernel<<<704, 256, 0, stream>>>(qkvw, projw, fc1w, fc2w, wq, wp, w1, w2);

    // norm1 (+ raw fp32 transpose for residual), bf16 out
    norm_kernel<<<4096, 256, 0, stream>>>(x, n1w, n1b, img, xT, 1);
    // qkv = img @ qkv_w^T -> bf16 (16384 x 512)
    mfma_gemm<<<dim3(8, 256), 256, 0, stream>>>(img, wq, nullptr, nullptr, qkv, 512, 256, 1);
    // MFMA windowed attention + fused LePE -> bf16 att (query-split x2)
    attn_kernel<<<512, 512, 0, stream>>>(qkv, gw0, gb0, gw1, gb1, att);
    // out = xT + att @ proj_w^T + proj_b (fp32)
    mfma_gemm<<<dim3(4, 256), 256, 0, stream>>>(att, wp, projb, xT, out, 256, 256, 3);
    // norm2 -> bf16
    norm_kernel<<<4096, 256, 0, stream>>>(out, n2w, n2b, ynorm, nullptr, 0);
    // fc1: gelu -> bf16 hidden (16384 x 1024)
    mfma_gemm<<<dim3(16, 256), 256, 0, stream>>>(ynorm, w1, fc1b, nullptr, hidden, 1024, 256, 2);
    // fc2: + bias + resid(out) -> out (16384 x 256)
    mfma_gemm<<<dim3(4, 256), 256, 0, stream>>>(hidden, w2, fc2b, out, out, 256, 1024, 3);
}

// Round 11
// 159.279 us; speedup vs baseline: 1.0357x; 1.0357x over previous
//
#include <hip/hip_runtime.h>
#include <hip/hip_bf16.h>

// Problem geometry (fixed)
#define BDIM 4
#define CDIM 256
#define HDIM 64
#define WDIM 64
#define LDIM 4096   // H*W
#define ROWS 16384  // B*L

typedef __attribute__((ext_vector_type(8))) short short8;
typedef __attribute__((ext_vector_type(4))) float f32x4;
typedef __attribute__((ext_vector_type(16))) float f32x16;
typedef unsigned int u32;

static __device__ __forceinline__ unsigned short f2bf(float f) {
    unsigned int x = __float_as_uint(f);
    unsigned int r = (x + 0x7fffu + ((x >> 16) & 1u)) >> 16;   // RNE
    return (unsigned short)r;
}
static __device__ __forceinline__ float bf2f(unsigned int u) {
    return __uint_as_float(u << 16);
}
static __device__ __forceinline__ u32 pk2(float a, float b) {
    return (u32)f2bf(a) | ((u32)f2bf(b) << 16);
}

// ---------------------------------------------------------------------------
// prep: weight fp32->bf16 (blocks 0..703) + norm1 with transpose (704..4799)
// ---------------------------------------------------------------------------
__global__ __launch_bounds__(256) void prep_kernel(
    const float* __restrict__ x,
    const float* __restrict__ n1w, const float* __restrict__ n1b,
    unsigned short* __restrict__ img, float* __restrict__ xT,
    const float* __restrict__ qkvw, const float* __restrict__ projw,
    const float* __restrict__ fc1w, const float* __restrict__ fc2w,
    unsigned short* __restrict__ wq, unsigned short* __restrict__ wp,
    unsigned short* __restrict__ w1, unsigned short* __restrict__ w2)
{
    int blk = blockIdx.x;
    if (blk < 704) {
        int i = blk * 256 + threadIdx.x;
        const float* in; unsigned short* out; int off;
        if (i < 32768)       { in = qkvw; out = wq; off = i; }
        else if (i < 49152)  { in = projw; out = wp; off = i - 32768; }
        else if (i < 114688) { in = fc1w; out = w1; off = i - 49152; }
        else if (i < 180224) { in = fc2w; out = w2; off = i - 114688; }
        else return;
        float4 f = reinterpret_cast<const float4*>(in)[off];
        reinterpret_cast<uint2*>(out)[off] = make_uint2(pk2(f.x, f.y), pk2(f.z, f.w));
        return;
    }
    int wave = threadIdx.x >> 6;
    int lane = threadIdx.x & 63;
    int row = (blk - 704) * 4 + wave;
    int bb = row >> 12;
    int l = row & 4095;
    const float* xb = x + (size_t)bb * (CDIM * LDIM) + l;
    float v[4];
    float sum = 0.f, sumsq = 0.f;
    #pragma unroll
    for (int i = 0; i < 4; ++i) {
        int c = lane + i * 64;
        float t = xb[(size_t)c * LDIM];
        v[i] = t; sum += t; sumsq += t * t;
    }
    #pragma unroll
    for (int off = 32; off > 0; off >>= 1) {
        sum   += __shfl_xor(sum, off);
        sumsq += __shfl_xor(sumsq, off);
    }
    float mean = sum * (1.f / 256.f);
    float var  = sumsq * (1.f / 256.f) - mean * mean;
    float inv  = rsqrtf(var + 1e-5f);
    unsigned short* orow = img + (size_t)row * CDIM;
    #pragma unroll
    for (int i = 0; i < 4; ++i) {
        int c = lane + i * 64;
        xT[(size_t)row * CDIM + c] = v[i];
        orow[c] = f2bf((v[i] - mean) * inv * n1w[c] + n1b[c]);
    }
}

// ---------------------------------------------------------------------------
// LayerNorm over C=256 (row-contiguous input) -> bf16 out.   (norm2)
// ---------------------------------------------------------------------------
__global__ __launch_bounds__(256) void norm_kernel(
    const float* __restrict__ xin,
    const float* __restrict__ w, const float* __restrict__ b,
    unsigned short* __restrict__ out)
{
    int wave = threadIdx.x >> 6;
    int lane = threadIdx.x & 63;
    int row = blockIdx.x * 4 + wave;
    const float* xr = xin + (size_t)row * CDIM;
    float v[4];
    float sum = 0.f, sumsq = 0.f;
    #pragma unroll
    for (int i = 0; i < 4; ++i) {
        float t = xr[lane + i * 64];
        v[i] = t; sum += t; sumsq += t * t;
    }
    #pragma unroll
    for (int off = 32; off > 0; off >>= 1) {
        sum   += __shfl_xor(sum, off);
        sumsq += __shfl_xor(sumsq, off);
    }
    float mean = sum * (1.f / 256.f);
    float var  = sumsq * (1.f / 256.f) - mean * mean;
    float inv  = rsqrtf(var + 1e-5f);
    unsigned short* orow = out + (size_t)row * CDIM;
    #pragma unroll
    for (int i = 0; i < 4; ++i) {
        int c = lane + i * 64;
        orow[c] = f2bf((v[i] - mean) * inv * w[c] + b[c]);
    }
}

// ---------------------------------------------------------------------------
// bf16 MFMA GEMM: C = A @ B^T (+ bias / gelu / resid), fp32 accumulate.
// 64x64 tile, BK=64 (2 sub-steps of K=32), 4 waves (2x2), 2x2 frags/wave.
// Double-buffered global_load_lds staging (linear LDS dest, pre-swizzled
// global source granule g = p ^ (row&7)); reads XOR the same pattern.
// Halves barrier count vs BK=32 (K=256: 4 sync points). Bijective XCD swizzle.
// mode: 0 plain->f32; 1 plain->bf16; 2 +bias,gelu(tanh)->bf16; 3 +bias+resid->f32
// ---------------------------------------------------------------------------
__global__ __launch_bounds__(256) void mfma_gemm(
    const unsigned short* __restrict__ A,
    const unsigned short* __restrict__ Bm,
    const float* __restrict__ bias,
    const float* __restrict__ resid,
    void* __restrict__ outp,
    int N, int K, int mode)
{
    __shared__ unsigned short As[2][64 * 64];
    __shared__ unsigned short Bs[2][64 * 64];
    int tid  = threadIdx.x;
    int lane = tid & 63;
    int w    = tid >> 6;
    int wr   = w >> 1, wc = w & 1;
    int l15  = lane & 15, kbl = lane >> 4;

    int gx  = gridDim.x;
    int nwg = gx * gridDim.y;
    int bid = blockIdx.y * gx + blockIdx.x;
    int cpx = nwg >> 3;
    int swz = (bid & 7) * cpx + (bid >> 3);
    int n0 = (swz % gx) * 64;
    int m0 = (swz / gx) * 64;

    f32x4 acc[2][2];
    #pragma unroll
    for (int m = 0; m < 2; ++m)
        #pragma unroll
        for (int n = 0; n < 2; ++n)
            acc[m][n] = (f32x4){0.f, 0.f, 0.f, 0.f};

    // staging: 512 chunks of 16B per matrix per BK=64 tile; 2 per thread.
    // chunk c: row=c>>3, phys slot p=c&7, global granule g = p ^ (row&7)
    auto STAGE = [&](int buf, int k0) {
        #pragma unroll
        for (int i = 0; i < 2; ++i) {
            int c = i * 256 + tid;
            int row = c >> 3, p = c & 7;
            int g = p ^ (row & 7);
            const unsigned short* ga = A  + (size_t)(m0 + row) * K + k0 + g * 8;
            const unsigned short* gb = Bm + (size_t)(n0 + row) * K + k0 + g * 8;
            __builtin_amdgcn_global_load_lds(
                (const __attribute__((address_space(1))) void*)ga,
                (__attribute__((address_space(3))) void*)(As[buf] + c * 8), 16, 0, 0);
            __builtin_amdgcn_global_load_lds(
                (const __attribute__((address_space(1))) void*)gb,
                (__attribute__((address_space(3))) void*)(Bs[buf] + c * 8), 16, 0, 0);
        }
    };

    STAGE(0, 0);
    __syncthreads();

    int cur = 0;
    for (int k0 = 0; k0 < K; k0 += 64) {
        if (k0 + 64 < K) STAGE(cur ^ 1, k0 + 64);

        #pragma unroll
        for (int ks = 0; ks < 2; ++ks) {
            int kg = ks * 4 + kbl;
            short8 af[2], bf[2];
            #pragma unroll
            for (int m = 0; m < 2; ++m) {
                int row = wr * 32 + m * 16 + l15;
                af[m] = *reinterpret_cast<const short8*>(
                    As[cur] + row * 64 + (kg ^ (row & 7)) * 8);
            }
            #pragma unroll
            for (int n = 0; n < 2; ++n) {
                int row = wc * 32 + n * 16 + l15;
                bf[n] = *reinterpret_cast<const short8*>(
                    Bs[cur] + row * 64 + (kg ^ (row & 7)) * 8);
            }
            #pragma unroll
            for (int m = 0; m < 2; ++m)
                #pragma unroll
                for (int n = 0; n < 2; ++n)
                    acc[m][n] = __builtin_amdgcn_mfma_f32_16x16x32_bf16(
                        af[m], bf[n], acc[m][n], 0, 0, 0);
        }

        __syncthreads();
        cur ^= 1;
    }

    int r0 = kbl * 4;
    #pragma unroll
    for (int m = 0; m < 2; ++m) {
        #pragma unroll
        for (int n = 0; n < 2; ++n) {
            int col = n0 + wc * 32 + n * 16 + l15;
            #pragma unroll
            for (int r = 0; r < 4; ++r) {
                int row = m0 + wr * 32 + m * 16 + r0 + r;
                float v = acc[m][n][r];
                if (mode == 0) {
                    ((float*)outp)[(size_t)row * N + col] = v;
                } else if (mode == 1) {
                    ((unsigned short*)outp)[(size_t)row * N + col] = f2bf(v);
                } else if (mode == 2) {
                    v += bias[col];
                    // tanh-form GELU: 0.5v(1+tanh(0.79788456(v+0.044715v^3)))
                    float u = v * (0.7978845608f + 0.0356774081f * v * v);
                    float t = exp2f(-2.8853900818f * fabsf(u));
                    float th = __fdividef(1.f - t, 1.f + t);
                    th = copysignf(th, u);
                    v = 0.5f * v * (1.f + th);
                    ((unsigned short*)outp)[(size_t)row * N + col] = f2bf(v);
                } else {
                    v += bias[col] + resid[(size_t)row * N + col];
                    ((float*)outp)[(size_t)row * N + col] = v;
                }
            }
        }
    }
}

// ---------------------------------------------------------------------------
// MFMA windowed attention + fused LePE (R8 version — best measured).
// One block per (window, head): 512 thr; each wave does two 32-q slices.
// Swapped QK^T; online softmax lane-local; P->bf16 + partner shfl; swapped PV.
// K (pre-scaled) and V^T staged in LDS with both-sides XOR slot swizzles.
// LePE 3x3 depthwise computed in the epilogue from the LDS V^T tile.
// ---------------------------------------------------------------------------
__global__ __launch_bounds__(512) void attn_kernel(
    const unsigned short* __restrict__ qkv,   // ROWS x 512 bf16
    const float* __restrict__ gw0, const float* __restrict__ gb0,
    const float* __restrict__ gw1, const float* __restrict__ gb1,
    unsigned short* __restrict__ att)         // ROWS x 256 bf16
{
    __shared__ unsigned short Kbuf[512 * 32]; // [row][d], slot ^= (row>>1)&3
    __shared__ unsigned short Vt[32 * 512];   // [d][key], slot ^= d&7
    __shared__ float gwl[288];
    __shared__ float gbl[32];
    const int wh = blockIdx.x;
    const int br = wh >> 7, head = wh & 3, win = (wh >> 2) & 31;
    const int bb = win >> 3, wi = win & 7;
    const int tid = threadIdx.x;
    const int qk_off = br * 128 + head * 32;
    const int v_off = 256 + qk_off;
    const float sscale = 0.42044820762685725f;  // 32^-0.25 = sqrt(scale)

    {
        const float* gw = br ? gw1 : gw0;
        const float* gb = br ? gb1 : gb0;
        if (tid < 288) gwl[tid] = gw[(head * 32) * 9 + tid];
        else if (tid >= 480) gbl[tid - 480] = gb[head * 32 + tid - 480];
    }
    // ---- stage K (scaled) ----
    {
        int t = tid;
        int l = (br == 0) ? ((t >> 3) * 64 + wi * 8 + (t & 7)) : (wi * 512 + t);
        const unsigned short* src = qkv + ((size_t)(bb * 4096 + l)) * 512 + qk_off;
        #pragma unroll
        for (int s = 0; s < 4; ++s) {
            uint4 raw = *reinterpret_cast<const uint4*>(src + s * 8);
            u32 rw[4] = {raw.x, raw.y, raw.z, raw.w};
            u32 ow[4];
            #pragma unroll
            for (int i = 0; i < 4; ++i) {
                float lo = bf2f(rw[i] & 0xffffu) * sscale;
                float hi = bf2f(rw[i] >> 16) * sscale;
                ow[i] = pk2(lo, hi);
            }
            int sl = s ^ ((t >> 1) & 3);
            *reinterpret_cast<uint4*>(Kbuf + t * 32 + sl * 8) =
                make_uint4(ow[0], ow[1], ow[2], ow[3]);
        }
    }
    // ---- stage V transposed ----
    {
        int kp = (tid & 255) * 2, dh = tid >> 8;
        int kq = kp + 1;
        int l0 = (br == 0) ? ((kp >> 3) * 64 + wi * 8 + (kp & 7)) : (wi * 512 + kp);
        int l1 = (br == 0) ? ((kq >> 3) * 64 + wi * 8 + (kq & 7)) : (wi * 512 + kq);
        const unsigned short* v0 = qkv + ((size_t)(bb * 4096 + l0)) * 512 + v_off + dh * 16;
        const unsigned short* v1 = qkv + ((size_t)(bb * 4096 + l1)) * 512 + v_off + dh * 16;
        uint4 a0 = *reinterpret_cast<const uint4*>(v0);
        uint4 a1 = *reinterpret_cast<const uint4*>(v0 + 8);
        uint4 b0 = *reinterpret_cast<const uint4*>(v1);
        uint4 b1 = *reinterpret_cast<const uint4*>(v1 + 8);
        u32 av[8] = {a0.x, a0.y, a0.z, a0.w, a1.x, a1.y, a1.z, a1.w};
        u32 bv[8] = {b0.x, b0.y, b0.z, b0.w, b1.x, b1.y, b1.z, b1.w};
        int slot = kp >> 3;
        #pragma unroll
        for (int dd = 0; dd < 16; ++dd) {
            u32 x0 = (dd & 1) ? (av[dd >> 1] >> 16) : (av[dd >> 1] & 0xffffu);
            u32 x1 = (dd & 1) ? (bv[dd >> 1] >> 16) : (bv[dd >> 1] & 0xffffu);
            int d = dh * 16 + dd;
            int sl = slot ^ (d & 7);
            *reinterpret_cast<u32*>(Vt + d * 512 + sl * 8 + (kp & 7)) = x0 | (x1 << 16);
        }
    }
    __syncthreads();

    const int lane = tid & 63;
    const int w = tid >> 6;
    const int ql = lane & 31;
    const int h = lane >> 5;
    const int q0 = w * 64;

    f32x16 O0, O1;
    #pragma unroll
    for (int i = 0; i < 16; ++i) { O0[i] = 0.f; O1[i] = 0.f; }
    float m0 = -1e30f, m1 = -1e30f, su0 = 0.f, su1 = 0.f;

    auto process = [&](int QS, f32x16& O, float& M, float& SU,
                       short8 kf0, short8 kf1, short8 vf0, short8 vf1) {
        int qrow = q0 + QS * 32 + ql;
        int sw = (qrow >> 1) & 3;
        short8 qf0 = *reinterpret_cast<const short8*>(Kbuf + qrow * 32 + ((0 + h) ^ sw) * 8);
        short8 qf1 = *reinterpret_cast<const short8*>(Kbuf + qrow * 32 + ((2 + h) ^ sw) * 8);
        f32x16 sacc;
        #pragma unroll
        for (int i = 0; i < 16; ++i) sacc[i] = 0.f;
        sacc = __builtin_amdgcn_mfma_f32_32x32x16_bf16(kf0, qf0, sacc, 0, 0, 0);
        sacc = __builtin_amdgcn_mfma_f32_32x32x16_bf16(kf1, qf1, sacc, 0, 0, 0);
        float mx = sacc[0];
        #pragma unroll
        for (int r = 1; r < 16; ++r) mx = fmaxf(mx, sacc[r]);
        mx = fmaxf(mx, __shfl_xor(mx, 32));
        float nm = fmaxf(M, mx);
        float fs = __expf(M - nm);
        M = nm;
        float p[16];
        float ps = 0.f;
        #pragma unroll
        for (int r = 0; r < 16; ++r) { p[r] = __expf(sacc[r] - nm); ps += p[r]; }
        ps += __shfl_xor(ps, 32);
        SU = SU * fs + ps;
        u32 P[8];
        #pragma unroll
        for (int g = 0; g < 4; ++g) {
            P[2 * g]     = pk2(p[4 * g],     p[4 * g + 1]);
            P[2 * g + 1] = pk2(p[4 * g + 2], p[4 * g + 3]);
        }
        u32 X[8];
        #pragma unroll
        for (int i = 0; i < 8; ++i) X[i] = __shfl_xor(P[i], 32);
        union { u32 u[4]; short8 s; } c0, c1;
        c0.u[0] = h ? X[2] : P[0];  c0.u[1] = h ? X[3] : P[1];
        c0.u[2] = h ? P[2] : X[0];  c0.u[3] = h ? P[3] : X[1];
        c1.u[0] = h ? X[6] : P[4];  c1.u[1] = h ? X[7] : P[5];
        c1.u[2] = h ? P[6] : X[4];  c1.u[3] = h ? P[7] : X[5];
        #pragma unroll
        for (int r = 0; r < 16; ++r) O[r] *= fs;
        O = __builtin_amdgcn_mfma_f32_32x32x16_bf16(vf0, c0.s, O, 0, 0, 0);
        O = __builtin_amdgcn_mfma_f32_32x32x16_bf16(vf1, c1.s, O, 0, 0, 0);
    };

    for (int kt = 0; kt < 16; ++kt) {
        int k0 = kt * 32;
        int krow = k0 + ql;
        int ksw = (krow >> 1) & 3;
        short8 kf0 = *reinterpret_cast<const short8*>(Kbuf + krow * 32 + ((0 + h) ^ ksw) * 8);
        short8 kf1 = *reinterpret_cast<const short8*>(Kbuf + krow * 32 + ((2 + h) ^ ksw) * 8);
        int ko0 = k0 + h * 8;
        int ko1 = k0 + 16 + h * 8;
        short8 vf0 = *reinterpret_cast<const short8*>(Vt + ql * 512 + ((ko0 >> 3) ^ (ql & 7)) * 8);
        short8 vf1 = *reinterpret_cast<const short8*>(Vt + ql * 512 + ((ko1 >> 3) ^ (ql & 7)) * 8);
        process(0, O0, m0, su0, kf0, kf1, vf0, vf1);
        process(1, O1, m1, su1, kf0, kf1, vf0, vf1);
    }

    // epilogue: normalize + fused LePE from LDS, write bf16.
    #pragma unroll
    for (int QS = 0; QS < 2; ++QS) {
        f32x16& O = QS ? O1 : O0;
        float inv = 1.f / (QS ? su1 : su0);
        int qrow = q0 + QS * 32 + ql;
        int hs  = (br == 0) ? (qrow >> 3) : (qrow >> 6);
        int wsx = (br == 0) ? (qrow & 7)  : (qrow & 63);

        float lep[16];
        #pragma unroll
        for (int r = 0; r < 16; ++r) {
            int d = (r & 3) + 8 * (r >> 2) + 4 * h;
            lep[r] = gbl[d];
        }
        #pragma unroll
        for (int dy = -1; dy <= 1; ++dy) {
            int hn = hs + dy;
            bool okh = (br == 0) ? ((unsigned)hn < 64u) : ((unsigned)hn < 8u);
            #pragma unroll
            for (int dx = -1; dx <= 1; ++dx) {
                int wn = wsx + dx;
                bool okw = (br == 0) ? ((unsigned)wn < 8u) : ((unsigned)wn < 64u);
                if (okh && okw) {
                    int key = (br == 0) ? (hn * 8 + wn) : (hn * 64 + wn);
                    int t = (dy + 1) * 3 + (dx + 1);
                    #pragma unroll
                    for (int r = 0; r < 16; ++r) {
                        int d = (r & 3) + 8 * (r >> 2) + 4 * h;
                        float vv = bf2f((u32)(unsigned short)
                            Vt[d * 512 + (((key >> 3) ^ (d & 7)) * 8 + (key & 7))]);
                        lep[r] += vv * gwl[d * 9 + t];
                    }
                }
            }
        }

        int l = (br == 0) ? ((qrow >> 3) * 64 + wi * 8 + (qrow & 7)) : (wi * 512 + qrow);
        unsigned short* orow = att + ((size_t)(bb * 4096 + l)) * 256 + qk_off;
        #pragma unroll
        for (int g = 0; g < 4; ++g) {
            u32 lo = pk2(O[4 * g] * inv + lep[4 * g],
                         O[4 * g + 1] * inv + lep[4 * g + 1]);
            u32 hi = pk2(O[4 * g + 2] * inv + lep[4 * g + 2],
                         O[4 * g + 3] * inv + lep[4 * g + 3]);
            *reinterpret_cast<uint2*>(orow + 8 * g + 4 * h) = make_uint2(lo, hi);
        }
    }
}

// ---------------------------------------------------------------------------
extern "C" void kernel_launch(void* const* d_in, const int* in_sizes, int n_in,
                              void* d_out, int out_size, void* d_ws, size_t ws_size,
                              hipStream_t stream) {
    const float* x     = (const float*)d_in[0];
    const float* n1w   = (const float*)d_in[1];
    const float* n1b   = (const float*)d_in[2];
    const float* qkvw  = (const float*)d_in[3];
    const float* gw0   = (const float*)d_in[4];
    const float* gb0   = (const float*)d_in[5];
    const float* gw1   = (const float*)d_in[6];
    const float* gb1   = (const float*)d_in[7];
    const float* projw = (const float*)d_in[8];
    const float* projb = (const float*)d_in[9];
    const float* n2w   = (const float*)d_in[10];
    const float* n2b   = (const float*)d_in[11];
    const float* fc1w  = (const float*)d_in[12];
    const float* fc1b  = (const float*)d_in[13];
    const float* fc2w  = (const float*)d_in[14];
    const float* fc2b  = (const float*)d_in[15];
    float* out = (float*)d_out;
    char* wsb  = (char*)d_ws;

    // workspace layout (bytes)
    float*          xT   = (float*)wsb;                          // 16,777,216
    unsigned short* qkv  = (unsigned short*)(wsb + 16777216);    // 16,777,216
    unsigned short* att  = (unsigned short*)(wsb + 33554432);    //  8,388,608
    unsigned short* img  = (unsigned short*)(wsb + 41943040);    //  8,388,608
    unsigned short* wq   = (unsigned short*)(wsb + 50331648);    //    262,144
    unsigned short* wp   = (unsigned short*)(wsb + 50593792);    //    131,072
    unsigned short* w1   = (unsigned short*)(wsb + 50724864);    //    524,288
    unsigned short* w2   = (unsigned short*)(wsb + 51249152);    //    524,288
    unsigned short* ynorm  = img;                                // reuse
    unsigned short* hidden = (unsigned short*)wsb;               // overlays xT+qkv (dead by fc1)

    // weights->bf16 + norm1(+transpose) in one launch
    prep_kernel<<<4800, 256, 0, stream>>>(x, n1w, n1b, img, xT,
                                          qkvw, projw, fc1w, fc2w, wq, wp, w1, w2);
    // qkv = img @ qkv_w^T -> bf16 (16384 x 512)
    mfma_gemm<<<dim3(8, 256), 256, 0, stream>>>(img, wq, nullptr, nullptr, qkv, 512, 256, 1);
    // MFMA windowed attention + fused LePE -> bf16 att
    attn_kernel<<<256, 512, 0, stream>>>(qkv, gw0, gb0, gw1, gb1, att);
    // out = xT + att @ proj_w^T + proj_b (fp32)
    mfma_gemm<<<dim3(4, 256), 256, 0, stream>>>(att, wp, projb, xT, out, 256, 256, 3);
    // norm2 -> bf16
    norm_kernel<<<4096, 256, 0, stream>>>(out, n2w, n2b, ynorm);
    // fc1: gelu -> bf16 hidden (16384 x 1024)
    mfma_gemm<<<dim3(16, 256), 256, 0, stream>>>(ynorm, w1, fc1b, nullptr, hidden, 1024, 256, 2);
    // fc2: + bias + resid(out) -> out (16384 x 256)
    mfma_gemm<<<dim3(4, 256), 256, 0, stream>>>(hidden, w2, fc2b, out, out, 256, 1024, 3);
}